// Round 2
// baseline (423.945 us; speedup 1.0000x reference)
//
#include <hip/hip_runtime.h>
#include <hip/hip_bf16.h>

using f32x4  = __attribute__((ext_vector_type(4))) float;
using bf16x8 = __attribute__((ext_vector_type(8))) short;

constexpr int BATCH = 8, SEQ = 1024, DIM = 768, NHEAD = 12, HDIM = 64;
constexpr int MROWS = BATCH * SEQ;   // 8192

__device__ __forceinline__ short f2bf(float f) {
    union { float f; unsigned u; } x; x.f = f;
    unsigned r = (x.u + 0x7fffu + ((x.u >> 16) & 1u)) >> 16;
    return (short)r;
}
__device__ __forceinline__ float fexp2(float x) { return __builtin_amdgcn_exp2f(x); }

// C = A[M,K] @ W[DIM,K]^T + bias   (nn.Linear semantics, NT GEMM)
// OMODE: 0 = bf16 row-major, 1 = fp32 row-major, 2 = bf16 V^T per-head [B][H][HDIM][SEQ]
template <typename AT, int OMODE>
__global__ __launch_bounds__(256)
void gemm_bt(const AT* __restrict__ A, const float* __restrict__ W,
             const float* __restrict__ bias, void* __restrict__ Cout) {
    constexpr int K  = DIM;
    constexpr int NT = DIM / 128;  // 6 column tiles
    __shared__ short As[128][72];
    __shared__ short Bs[128][72];

    const int bm = blockIdx.x / NT, bn = blockIdx.x % NT;
    const int m0 = bm * 128, n0 = bn * 128;
    const int t = threadIdx.x;
    const int lane = t & 63, w = t >> 6;
    const int wm = (w >> 1) * 64, wn = (w & 1) * 64;
    const int l16 = lane & 15, lg = lane >> 4;

    const int sr = t >> 1, sc = (t & 1) * 16;   // staging: 16 elems/thread

    f32x4 acc[4][4] = {};

    for (int k0 = 0; k0 < K; k0 += 32) {
        __syncthreads();
        if constexpr (sizeof(AT) == 4) {
            const float* ap = (const float*)A + (long)(m0 + sr) * K + k0 + sc;
            float tmp[16];
            *(f32x4*)&tmp[0]  = *(const f32x4*)(ap + 0);
            *(f32x4*)&tmp[4]  = *(const f32x4*)(ap + 4);
            *(f32x4*)&tmp[8]  = *(const f32x4*)(ap + 8);
            *(f32x4*)&tmp[12] = *(const f32x4*)(ap + 12);
            short tb[16];
            #pragma unroll
            for (int j = 0; j < 16; ++j) tb[j] = f2bf(tmp[j]);
            *(bf16x8*)&As[sr][sc]     = *(bf16x8*)&tb[0];
            *(bf16x8*)&As[sr][sc + 8] = *(bf16x8*)&tb[8];
        } else {
            const short* ap = (const short*)A + (long)(m0 + sr) * K + k0 + sc;
            *(bf16x8*)&As[sr][sc]     = *(const bf16x8*)(ap);
            *(bf16x8*)&As[sr][sc + 8] = *(const bf16x8*)(ap + 8);
        }
        {
            const float* wp = W + (long)(n0 + sr) * K + k0 + sc;
            float tmp[16];
            *(f32x4*)&tmp[0]  = *(const f32x4*)(wp + 0);
            *(f32x4*)&tmp[4]  = *(const f32x4*)(wp + 4);
            *(f32x4*)&tmp[8]  = *(const f32x4*)(wp + 8);
            *(f32x4*)&tmp[12] = *(const f32x4*)(wp + 12);
            short tb[16];
            #pragma unroll
            for (int j = 0; j < 16; ++j) tb[j] = f2bf(tmp[j]);
            *(bf16x8*)&Bs[sr][sc]     = *(bf16x8*)&tb[0];
            *(bf16x8*)&Bs[sr][sc + 8] = *(bf16x8*)&tb[8];
        }
        __syncthreads();

        bf16x8 af[4], bfg[4];
        const int kc = lg * 8;
        #pragma unroll
        for (int mi = 0; mi < 4; ++mi)
            af[mi] = *(const bf16x8*)&As[wm + mi * 16 + l16][kc];
        #pragma unroll
        for (int ni = 0; ni < 4; ++ni)
            bfg[ni] = *(const bf16x8*)&Bs[wn + ni * 16 + l16][kc];
        #pragma unroll
        for (int mi = 0; mi < 4; ++mi)
            #pragma unroll
            for (int ni = 0; ni < 4; ++ni)
                acc[mi][ni] = __builtin_amdgcn_mfma_f32_16x16x32_bf16(
                    af[mi], bfg[ni], acc[mi][ni], 0, 0, 0);
    }

    // epilogue: C/D layout col=lane&15, row=(lane>>4)*4+j
    #pragma unroll
    for (int mi = 0; mi < 4; ++mi) {
        const int row = m0 + wm + mi * 16 + lg * 4;
        #pragma unroll
        for (int ni = 0; ni < 4; ++ni) {
            const int col = n0 + wn + ni * 16 + l16;
            const float bv = bias[col];
            #pragma unroll
            for (int j = 0; j < 4; ++j) {
                float val = acc[mi][ni][j] + bv;
                if constexpr (OMODE == 0) {
                    ((short*)Cout)[(long)(row + j) * DIM + col] = f2bf(val);
                } else if constexpr (OMODE == 1) {
                    ((float*)Cout)[(long)(row + j) * DIM + col] = val;
                } else {
                    // V^T per-head: [B][H][HDIM][SEQ]
                    const int bb = row / SEQ;          // constant per block (128 | 1024)
                    const int tok = (row % SEQ) + j;
                    const int hh = col >> 6, dd = col & 63;
                    ((short*)Cout)[((long)(bb * NHEAD + hh) * HDIM + dd) * SEQ + tok] = f2bf(val);
                }
            }
        }
    }
}

// Flash attention with bias + mask. Block = (b, h, 64 q-rows); 4 waves x 16 q-rows.
// K read row-major from global (L2-resident); V read from per-head V^T layout.
// No barriers: only per-wave P LDS roundtrip.
__global__ __launch_bounds__(256)
void attn_kernel(const short* __restrict__ Qp, const short* __restrict__ Kp,
                 const short* __restrict__ Vt, const float* __restrict__ bias,
                 const int* __restrict__ mask, short* __restrict__ Op) {
    __shared__ short Ps[4][16][72];   // per-wave P [qrow][key]

    const int bid = blockIdx.x;
    const int qt = bid & 15;                 // SEQ/64 = 16 q-tiles
    const int h  = (bid >> 4) % NHEAD;
    const int b  = bid / (16 * NHEAD);
    const int t = threadIdx.x;
    const int lane = t & 63, w = t >> 6;
    const int l16 = lane & 15, lg = lane >> 4;

    // Q fragments: rows w*16 + l16, k = lg*8 (+0 / +32)
    const int qrow = qt * 64 + w * 16 + l16;
    const short* qptr = Qp + (long)(b * SEQ + qrow) * DIM + h * HDIM + lg * 8;
    const bf16x8 qf0 = *(const bf16x8*)qptr;
    const bf16x8 qf1 = *(const bf16x8*)(qptr + 32);

    const int qg = qt * 64 + w * 16 + lg * 4;               // + j
    const float* bias_base = bias + ((long)(b * NHEAD + h) * SEQ + qg) * SEQ + l16;
    const int*   mask_base = mask + ((long)b * SEQ + qg) * SEQ + l16;
    const short* kbase = Kp + (long)b * SEQ * DIM + h * HDIM + lg * 8;          // +(key)*DIM
    const short* vbase = Vt + ((long)(b * NHEAD + h) * HDIM + l16) * SEQ + lg * 8; // +df*16*SEQ +kt*64

    f32x4 acc_o[4] = {};
    float m_run[4], l_run[4];
    #pragma unroll
    for (int j = 0; j < 4; ++j) { m_run[j] = -1e30f; l_run[j] = 0.f; }

    constexpr float L2E = 1.4426950408889634f;

    for (int kt = 0; kt < SEQ / 64; ++kt) {
        // S = Q K^T: B-fragments straight from global K rows
        f32x4 s[4];
        #pragma unroll
        for (int c = 0; c < 4; ++c) {
            const short* kp = kbase + (long)(kt * 64 + c * 16 + l16) * DIM;
            const bf16x8 kb0 = *(const bf16x8*)kp;
            const bf16x8 kb1 = *(const bf16x8*)(kp + 32);
            f32x4 z = {};
            z    = __builtin_amdgcn_mfma_f32_16x16x32_bf16(qf0, kb0, z, 0, 0, 0);
            s[c] = __builtin_amdgcn_mfma_f32_16x16x32_bf16(qf1, kb1, z, 0, 0, 0);
        }

        // scale + bias + mask
        float p[4][4], mt[4];
        #pragma unroll
        for (int j = 0; j < 4; ++j) mt[j] = -1e30f;
        #pragma unroll
        for (int c = 0; c < 4; ++c) {
            const int kg = kt * 64 + c * 16;
            #pragma unroll
            for (int j = 0; j < 4; ++j) {
                float sv = s[c][j] * 0.125f + bias_base[(long)j * SEQ + kg];
                const int mv = mask_base[(long)j * SEQ + kg];
                sv = mv ? sv : -1e30f;
                p[c][j] = sv;
                mt[j] = fmaxf(mt[j], sv);
            }
        }
        // row-max across the 16-lane group
        #pragma unroll
        for (int off = 1; off < 16; off <<= 1)
            #pragma unroll
            for (int j = 0; j < 4; ++j)
                mt[j] = fmaxf(mt[j], __shfl_xor(mt[j], off));

        float alpha[4], lt[4];
        #pragma unroll
        for (int j = 0; j < 4; ++j) {
            const float mn = fmaxf(m_run[j], mt[j]);
            alpha[j] = fexp2((m_run[j] - mn) * L2E);
            m_run[j] = mn;
            lt[j] = 0.f;
        }
        #pragma unroll
        for (int c = 0; c < 4; ++c)
            #pragma unroll
            for (int j = 0; j < 4; ++j) {
                const float e = fexp2((p[c][j] - m_run[j]) * L2E);
                p[c][j] = e;
                lt[j] += e;
            }
        #pragma unroll
        for (int off = 1; off < 16; off <<= 1)
            #pragma unroll
            for (int j = 0; j < 4; ++j)
                lt[j] += __shfl_xor(lt[j], off);
        #pragma unroll
        for (int j = 0; j < 4; ++j)
            l_run[j] = l_run[j] * alpha[j] + lt[j];

        // rescale O accumulators
        #pragma unroll
        for (int df = 0; df < 4; ++df)
            #pragma unroll
            for (int j = 0; j < 4; ++j)
                acc_o[df][j] *= alpha[j];

        // P (C-layout) -> per-wave LDS -> A-fragments (wave-internal, no barrier)
        #pragma unroll
        for (int c = 0; c < 4; ++c)
            #pragma unroll
            for (int j = 0; j < 4; ++j)
                Ps[w][lg * 4 + j][c * 16 + l16] = f2bf(p[c][j]);

        const bf16x8 pa0 = *(const bf16x8*)&Ps[w][l16][lg * 8];
        const bf16x8 pa1 = *(const bf16x8*)&Ps[w][l16][32 + lg * 8];

        // PV: B-fragments straight from global V^T
        #pragma unroll
        for (int df = 0; df < 4; ++df) {
            const short* vp = vbase + (long)df * 16 * SEQ + kt * 64;
            const bf16x8 vb0 = *(const bf16x8*)vp;
            const bf16x8 vb1 = *(const bf16x8*)(vp + 32);
            acc_o[df] = __builtin_amdgcn_mfma_f32_16x16x32_bf16(pa0, vb0, acc_o[df], 0, 0, 0);
            acc_o[df] = __builtin_amdgcn_mfma_f32_16x16x32_bf16(pa1, vb1, acc_o[df], 0, 0, 0);
        }
    }

    // epilogue: O /= l, write bf16 to Op[b, q, h*64+d]
    #pragma unroll
    for (int df = 0; df < 4; ++df) {
        #pragma unroll
        for (int j = 0; j < 4; ++j) {
            const float val = acc_o[df][j] / fmaxf(l_run[j], 1e-20f);
            const int row = b * SEQ + qt * 64 + w * 16 + lg * 4 + j;
            const int col = h * HDIM + df * 16 + l16;
            Op[(long)row * DIM + col] = f2bf(val);
        }
    }
}

extern "C" void kernel_launch(void* const* d_in, const int* in_sizes, int n_in,
                              void* d_out, int out_size, void* d_ws, size_t ws_size,
                              hipStream_t stream) {
    const float* q         = (const float*)d_in[0];
    const float* k         = (const float*)d_in[1];
    const float* v         = (const float*)d_in[2];
    const float* attn_bias = (const float*)d_in[3];
    const int*   attn_mask = (const int*)d_in[4];
    const float* Wq = (const float*)d_in[5];
    const float* bq = (const float*)d_in[6];
    const float* Wk = (const float*)d_in[7];
    const float* bk = (const float*)d_in[8];
    const float* Wv = (const float*)d_in[9];
    const float* bv = (const float*)d_in[10];
    const float* Wo = (const float*)d_in[11];
    const float* bo = (const float*)d_in[12];
    float* out = (float*)d_out;

    short* Qp = (short*)d_ws;                    // [8192][768] bf16
    short* Kp = Qp + (long)MROWS * DIM;
    short* Vt = Kp + (long)MROWS * DIM;          // [B][H][64][1024] bf16
    short* Op = Vt + (long)MROWS * DIM;

    const dim3 blk(256);
    const int gemm_grid = (MROWS / 128) * (DIM / 128);   // 64*6 = 384

    gemm_bt<float, 0><<<gemm_grid, blk, 0, stream>>>(q, Wq, bq, Qp);
    gemm_bt<float, 0><<<gemm_grid, blk, 0, stream>>>(k, Wk, bk, Kp);
    gemm_bt<float, 2><<<gemm_grid, blk, 0, stream>>>(v, Wv, bv, Vt);

    const int attn_grid = BATCH * NHEAD * (SEQ / 64);    // 1536
    attn_kernel<<<attn_grid, blk, 0, stream>>>(Qp, Kp, Vt, attn_bias, attn_mask, Op);

    gemm_bt<short, 1><<<gemm_grid, blk, 0, stream>>>(Op, Wo, bo, out);
}